// Round 15
// baseline (253.284 us; speedup 1.0000x reference)
//
#include <hip/hip_runtime.h>
#include <hip/hip_fp16.h>

#define F 128
#define TILE 256          // nodes per dst-tile (main path)
#define TSH 8             // log2(TILE)
#define CHUNK 4096        // edges per bin block
#define BCAP 8192         // LDS stage capacity (ints) in build_tile; avg tile = 4082
#define ROWS2 32          // mid-path linear tile rows (R11-proven VALU kernel)
#define LINB 256
#define SCAN_TILE 1024    // mid-path (round-3 proven) tile

typedef _Float16 f16x8 __attribute__((ext_vector_type(8)));
typedef float f32x4 __attribute__((ext_vector_type(4)));

__device__ inline float4 h8_to_f4(uint2 u) {
    union { unsigned int x; __half2 h; } a, b;
    a.x = u.x; b.x = u.y;
    const float2 lo = __half22float2(a.h);
    const float2 hi = __half22float2(b.h);
    return make_float4(lo.x, lo.y, hi.x, hi.y);
}

// ============================================================================
// Fused prep + A1 count (round-12 proven):
//  blocks [0, NCHUNK): per-chunk tile histogram into LDS -> blkCnt.
//  blocks [NCHUNK, ...): feat fp32->fp16; W fp32->fp16 element-wise ([o][k]
//    = MFMA B-operand layout); offsets[N] fix; zero the agg work-steal cursor.
// ============================================================================
__global__ __launch_bounds__(256) void prep_count_kernel(
        const float* __restrict__ feat, unsigned int* __restrict__ featH,
        const float* __restrict__ W, __half* __restrict__ woh,
        int* __restrict__ offsets, const int* __restrict__ dst,
        int* __restrict__ blkCnt, int* __restrict__ wcur,
        int N, int NF4, int E, int NT, int NCHUNK) {
    __shared__ int h[256];
    const int tid = threadIdx.x;
    const int bid = blockIdx.x;
    if (bid < NCHUNK) {
        h[tid] = 0;
        __syncthreads();
        const int e0 = bid * CHUNK;
        const int n = min(CHUNK, E - e0);
        for (int i = tid; i < n; i += 256) atomicAdd(&h[dst[e0 + i] >> TSH], 1);
        __syncthreads();
        if (tid < NT) blkCnt[(size_t)tid * NCHUNK + bid] = h[tid];
    } else {
        const int i = (bid - NCHUNK) * 256 + tid;
        if (i < NF4) {
            const float4 v = ((const float4*)feat)[i];
            union { __half2 h2; unsigned int u; } a, b;
            a.h2 = __floats2half2_rn(v.x, v.y);
            b.h2 = __floats2half2_rn(v.z, v.w);
            ((uint2*)featH)[i] = make_uint2(a.u, b.u);
        }
        if (i < F * F) woh[i] = __float2half(W[i]);
        if (i == 0) {
            if ((N & (TILE - 1)) == 0) offsets[N] = 0;
            *wcur = 0;
        }
    }
}

// ============================================================================
// A2 (parallel, round-5 proven): one block per tile row t.
// ============================================================================
__global__ __launch_bounds__(256) void binA_scan_kernel(
        const int* __restrict__ blkCnt, int* __restrict__ blkOff,
        int* __restrict__ bucketBase, int E, int NT, int NCHUNK) {
    __shared__ int red[256];
    const int t = blockIdx.x;
    const int tid = threadIdx.x;

    const int lim = t * NCHUNK;
    int s = 0;
    for (int i = tid; i < lim; i += 256) s += blkCnt[i];
    red[tid] = s;
    __syncthreads();
    for (int off = 128; off > 0; off >>= 1) {
        if (tid < off) red[tid] += red[tid + off];
        __syncthreads();
    }
    const int base = red[0];
    __syncthreads();

    int carry = base;
    for (int c0 = 0; c0 < NCHUNK; c0 += 256) {
        const int b = c0 + tid;
        const int v = (b < NCHUNK) ? blkCnt[(size_t)t * NCHUNK + b] : 0;
        red[tid] = v;
        __syncthreads();
        for (int off = 1; off < 256; off <<= 1) {
            int tv = (tid >= off) ? red[tid - off] : 0;
            __syncthreads();
            red[tid] += tv;
            __syncthreads();
        }
        const int excl = red[tid] - v;
        if (b < NCHUNK) blkOff[(size_t)t * NCHUNK + b] = carry + excl;
        const int tot = red[255];
        __syncthreads();
        carry += tot;
    }
    if (tid == 0) {
        bucketBase[t] = base;
        if (t == 0) bucketBase[NT] = E;
    }
}

// ============================================================================
// A3: deterministic scatter (round-5 proven).
// ============================================================================
__global__ __launch_bounds__(256) void binA_scatter_kernel(
        const int* __restrict__ src, const int* __restrict__ dst,
        const int* __restrict__ blkOff,
        unsigned int* __restrict__ edgebuf, int E, int NT, int NCHUNK) {
    __shared__ int h[256];
    __shared__ int lds2[256];
    __shared__ int cstart[256];
    __shared__ uint2 stage[CHUNK];
    const int tid = threadIdx.x, b = blockIdx.x;
    h[tid] = 0;
    __syncthreads();
    const int e0 = b * CHUNK;
    const int n = min(CHUNK, E - e0);
    for (int i = tid; i < n; i += 256) atomicAdd(&h[dst[e0 + i] >> TSH], 1);
    __syncthreads();
    const int myc = h[tid];
    lds2[tid] = myc;
    __syncthreads();
    for (int off = 1; off < 256; off <<= 1) {
        int t = (tid >= off) ? lds2[tid - off] : 0;
        __syncthreads();
        lds2[tid] += t;
        __syncthreads();
    }
    const int runstart = lds2[tid] - myc;
    if (tid < NT) cstart[tid] = blkOff[(size_t)tid * NCHUNK + b] - runstart;
    h[tid] = runstart;
    __syncthreads();
    for (int i = tid; i < n; i += 256) {
        const int e = e0 + i;
        const int d = dst[e];
        const int p = atomicAdd(&h[d >> TSH], 1);
        stage[p] = make_uint2((unsigned)src[e], (unsigned)d);
    }
    __syncthreads();
    for (int i = tid; i < n; i += 256) {
        const uint2 v = stage[i];
        const int t = (int)v.y >> TSH;
        edgebuf[cstart[t] + i] = (v.x << 8) | (v.y & 255u);
    }
}

// ============================================================================
// B: per-tile CSR finalize (round-5 proven).
// ============================================================================
__global__ __launch_bounds__(256) void build_tile_kernel(
        const unsigned int* __restrict__ edgebuf, const int* __restrict__ bucketBase,
        int* __restrict__ offsets, int* __restrict__ ssrc, int N, int NT) {
    __shared__ int h[TILE];
    __shared__ int excl[TILE];
    __shared__ int stage[BCAP];
    const int t = blockIdx.x, tid = threadIdx.x;
    const int s0 = bucketBase[t], s1 = bucketBase[t + 1];
    const int cnt = s1 - s0;
    const int n0 = t << TSH;
    const int n1 = min(n0 + TILE, N);
    h[tid] = 0;
    __syncthreads();
    for (int i = tid; i < cnt; i += 256)
        atomicAdd(&h[(int)(edgebuf[s0 + i] & 255u)], 1);
    __syncthreads();
    const int myv = h[tid];
    excl[tid] = myv;
    __syncthreads();
    for (int off = 1; off < 256; off <<= 1) {
        int tv = (tid >= off) ? excl[tid - off] : 0;
        __syncthreads();
        excl[tid] += tv;
        __syncthreads();
    }
    const int ex = excl[tid] - myv;
    const int v = n0 + tid;
    if (v < n1) offsets[v] = ex;
    if (tid == 255 && n1 == N && (N & (TILE - 1)) != 0) offsets[N] = excl[255];
    h[tid] = ex;
    __syncthreads();
    if (cnt <= BCAP) {
        for (int i = tid; i < cnt; i += 256) {
            const unsigned int e = edgebuf[s0 + i];
            const int p = atomicAdd(&h[(int)(e & 255u)], 1);
            stage[p] = (int)(e >> 8);
        }
        __syncthreads();
        for (int i = tid; i < cnt; i += 256) ssrc[s0 + i] = stage[i];
    } else {
        for (int i = tid; i < cnt; i += 256) {
            const unsigned int e = edgebuf[s0 + i];
            const int p = atomicAdd(&h[(int)(e & 255u)], 1);
            ssrc[s0 + p] = (int)(e >> 8);
        }
    }
}

// ============================================================================
// FUSED gather + MFMA, v3: R14's 4-wave cooperative block + WORK-STEALING.
// R14 counters: occ 56.5% (grid 3125 @ 8 blocks/CU = 1.53 scheduling rounds
// + barrier imbalance), hbm 2.28 TB/s. Fix: launch exactly 2048 blocks
// (8/CU) and steal tiles from a global cursor — light-tile blocks grab more,
// no second scheduling round, no static tail. 1 atomic / tile = noise.
// Barriers: 2/iter. Top barrier (after sh_t broadcast) doubles as the
// write-after-read fence: every wave's phase-B buf reads complete (drained
// before MFMA use) before it can reach the next top barrier.
// ============================================================================
__global__ __launch_bounds__(256) void agg_mfma_kernel(
        const uint4* __restrict__ fH,
        const int* __restrict__ ssrc,
        const int* __restrict__ offs,
        const int* __restrict__ base,
        const uint4* __restrict__ woh4,   // W[o][k] fp16, 128 rows x 16 uint4
        const float* __restrict__ bias,
        int* __restrict__ wcur,
        float* __restrict__ out, int N) {
    __shared__ __align__(16) uint4 buf[16 * 17];   // 16 rows x 272B = 4.25KB
    __shared__ int sh_t;
    const int tid = threadIdx.x;
    const int wid = tid >> 6;
    const int lane = tid & 63;
    const int g = lane >> 4;      // edge slot (A) / k-quarter (B)
    const int q = lane & 15;      // 16B chunk (A) / m16 (B)
    const int ntiles = (N + 15) >> 4;

    for (;;) {
        if (tid == 0) sh_t = atomicAdd(wcur, 1);
        __syncthreads();                    // broadcast + WAR fence for buf
        const int tile = sh_t;
        if (tile >= ntiles) break;
        const int v0 = tile << 4;

        // ---- phase A: wave wid aggregates its 4 nodes into LDS ----
#pragma unroll 1
        for (int t = 0; t < 4; ++t) {
            const int r16 = wid * 4 + t;
            const int v = v0 + r16;
            float a[8];
#pragma unroll
            for (int j = 0; j < 8; ++j) a[j] = 0.f;
            if (v < N) {
                const int s0 = offs[v] + base[v >> TSH];
                const int s1 = offs[v + 1] + base[(v + 1) >> TSH];
                int e = s0 + g;
                for (; e + 4 < s1; e += 8) {
                    const int i0 = ssrc[e], i1 = ssrc[e + 4];
                    const uint4 u0 = fH[(size_t)i0 * 16 + q];
                    const uint4 u1 = fH[(size_t)i1 * 16 + q];
                    {
                        union { unsigned int u; __half2 h; } c0, c1, c2, c3;
                        c0.u = u0.x; c1.u = u0.y; c2.u = u0.z; c3.u = u0.w;
                        const float2 f0 = __half22float2(c0.h);
                        const float2 f1 = __half22float2(c1.h);
                        const float2 f2 = __half22float2(c2.h);
                        const float2 f3 = __half22float2(c3.h);
                        a[0] += f0.x; a[1] += f0.y; a[2] += f1.x; a[3] += f1.y;
                        a[4] += f2.x; a[5] += f2.y; a[6] += f3.x; a[7] += f3.y;
                    }
                    {
                        union { unsigned int u; __half2 h; } c0, c1, c2, c3;
                        c0.u = u1.x; c1.u = u1.y; c2.u = u1.z; c3.u = u1.w;
                        const float2 f0 = __half22float2(c0.h);
                        const float2 f1 = __half22float2(c1.h);
                        const float2 f2 = __half22float2(c2.h);
                        const float2 f3 = __half22float2(c3.h);
                        a[0] += f0.x; a[1] += f0.y; a[2] += f1.x; a[3] += f1.y;
                        a[4] += f2.x; a[5] += f2.y; a[6] += f3.x; a[7] += f3.y;
                    }
                }
                for (; e < s1; e += 4) {
                    const uint4 u0 = fH[(size_t)ssrc[e] * 16 + q];
                    union { unsigned int u; __half2 h; } c0, c1, c2, c3;
                    c0.u = u0.x; c1.u = u0.y; c2.u = u0.z; c3.u = u0.w;
                    const float2 f0 = __half22float2(c0.h);
                    const float2 f1 = __half22float2(c1.h);
                    const float2 f2 = __half22float2(c2.h);
                    const float2 f3 = __half22float2(c3.h);
                    a[0] += f0.x; a[1] += f0.y; a[2] += f1.x; a[3] += f1.y;
                    a[4] += f2.x; a[5] += f2.y; a[6] += f3.x; a[7] += f3.y;
                }
            }
#pragma unroll
            for (int j = 0; j < 8; ++j) {
                a[j] += __shfl_xor(a[j], 16);
                a[j] += __shfl_xor(a[j], 32);
            }
            if (g == 0) {
                union { __half2 h2; unsigned int u; } p0, p1, p2, p3;
                p0.h2 = __floats2half2_rn(a[0], a[1]);
                p1.h2 = __floats2half2_rn(a[2], a[3]);
                p2.h2 = __floats2half2_rn(a[4], a[5]);
                p3.h2 = __floats2half2_rn(a[6], a[7]);
                buf[r16 * 17 + q] = make_uint4(p0.u, p1.u, p2.u, p3.u);
            }
        }
        __syncthreads();

        // ---- phase B: wave wid computes col-groups 2*wid, 2*wid+1 ----
        union U { uint4 u; f16x8 h; };
        U af0, af1, af2, af3;
        af0.u = buf[q * 17 + (g + 0)];
        af1.u = buf[q * 17 + (g + 4)];
        af2.u = buf[q * 17 + (g + 8)];
        af3.u = buf[q * 17 + (g + 12)];

#pragma unroll
        for (int j = 0; j < 2; ++j) {
            const int gg = wid * 2 + j;
            const uint4* wrow = woh4 + (size_t)(gg * 16 + q) * 16 + g;
            U b0, b1, b2, b3;
            b0.u = wrow[0]; b1.u = wrow[4]; b2.u = wrow[8]; b3.u = wrow[12];
            f32x4 acc = {0.f, 0.f, 0.f, 0.f};
            acc = __builtin_amdgcn_mfma_f32_16x16x32_f16(af0.h, b0.h, acc, 0, 0, 0);
            acc = __builtin_amdgcn_mfma_f32_16x16x32_f16(af1.h, b1.h, acc, 0, 0, 0);
            acc = __builtin_amdgcn_mfma_f32_16x16x32_f16(af2.h, b2.h, acc, 0, 0, 0);
            acc = __builtin_amdgcn_mfma_f32_16x16x32_f16(af3.h, b3.h, acc, 0, 0, 0);
            const float bv = bias[gg * 16 + q];
#pragma unroll
            for (int r = 0; r < 4; ++r) {
                const int gr = v0 + g * 4 + r;
                if (gr < N)
                    out[(size_t)gr * F + gg * 16 + q] = fmaxf(acc[r] + bv, 0.f);
            }
        }
    }
}

// ================= mid path (round-3/11 proven chain, fp32 gather) ==========
__global__ void prep2_kernel(const float* __restrict__ W, __half* __restrict__ wTh,
                             int* __restrict__ counts, int N) {
    int i = blockIdx.x * 256 + threadIdx.x;
    if (i < F * F) {
        int o = i >> 7, k = i & 127;
        wTh[k * F + o] = __float2half(W[i]);
    }
    if (i < N) counts[i] = 0;
}

__global__ void hist_kernel(const int* __restrict__ dst, int* __restrict__ counts, int E) {
    int e = blockIdx.x * blockDim.x + threadIdx.x;
    if (e < E) atomicAdd(&counts[dst[e]], 1);
}

__global__ __launch_bounds__(256) void scan1_kernel(const int* __restrict__ counts,
                                                    int* __restrict__ offsets,
                                                    int* __restrict__ cursor,
                                                    int* __restrict__ blockSums, int N) {
    __shared__ int lds[256];
    const int tid = threadIdx.x;
    const int i0 = blockIdx.x * SCAN_TILE + tid * 4;
    int v[4];
    int s = 0;
#pragma unroll
    for (int j = 0; j < 4; ++j) {
        int i = i0 + j;
        v[j] = (i < N) ? counts[i] : 0;
        s += v[j];
    }
    lds[tid] = s;
    __syncthreads();
    for (int off = 1; off < 256; off <<= 1) {
        int t = (tid >= off) ? lds[tid - off] : 0;
        __syncthreads();
        lds[tid] += t;
        __syncthreads();
    }
    int excl = lds[tid] - s;
#pragma unroll
    for (int j = 0; j < 4; ++j) {
        int i = i0 + j;
        if (i < N) {
            offsets[i] = excl;
            cursor[i] = excl;
        } else if (i == N) {
            offsets[N] = excl;
        }
        excl += v[j];
    }
    if (tid == 255) blockSums[blockIdx.x] = lds[255];
}

__global__ __launch_bounds__(256) void scan2_kernel(int* __restrict__ blockSums,
                                                    int* __restrict__ offsets,
                                                    int NB, int N) {
    __shared__ int lds[256];
    const int tid = threadIdx.x;
    int s = (tid < NB) ? blockSums[tid] : 0;
    lds[tid] = s;
    __syncthreads();
    for (int off = 1; off < 256; off <<= 1) {
        int t = (tid >= off) ? lds[tid - off] : 0;
        __syncthreads();
        lds[tid] += t;
        __syncthreads();
    }
    if (tid < NB) blockSums[tid] = lds[tid] - s;
    if (tid == NB && NB < 256) blockSums[NB] = lds[255];
    if (tid == 0 && (N & (SCAN_TILE - 1)) == 0) offsets[N] = 0;
}

__global__ void place_kernel(const int* __restrict__ src, const int* __restrict__ dst,
                             int* __restrict__ cursor, const int* __restrict__ base,
                             int* __restrict__ ssrc, int E) {
    int e = blockIdx.x * blockDim.x + threadIdx.x;
    if (e < E) {
        int d = dst[e];
        int pos = atomicAdd(&cursor[d], 1) + base[d >> 10];
        ssrc[pos] = src[e];
    }
}

__global__ __launch_bounds__(256) void agg_kernel(const float* __restrict__ feat,
                                                  const int* __restrict__ ssrc,
                                                  const int* __restrict__ offs,
                                                  const int* __restrict__ base,
                                                  float* __restrict__ out, int N) {
    const int gwave = (blockIdx.x * blockDim.x + threadIdx.x) >> 6;
    const int lane = threadIdx.x & 63;
    const int half = lane >> 5;
    const int q = lane & 31;
    const int nwaves = (gridDim.x * blockDim.x) >> 6;
    const float4* feat4 = (const float4*)feat;
    for (int v = gwave; v < N; v += nwaves) {
        const int s0 = offs[v] + base[v >> 10];
        const int s1 = offs[v + 1] + base[(v + 1) >> 10];
        float ax = 0.f, ay = 0.f, az = 0.f, aw = 0.f;
        int e = s0 + half;
        for (; e + 6 < s1; e += 8) {
            int i0 = ssrc[e], i1 = ssrc[e + 2], i2 = ssrc[e + 4], i3 = ssrc[e + 6];
            const float4 f0 = feat4[(size_t)i0 * 32 + q];
            const float4 f1 = feat4[(size_t)i1 * 32 + q];
            const float4 f2 = feat4[(size_t)i2 * 32 + q];
            const float4 f3 = feat4[(size_t)i3 * 32 + q];
            ax += (f0.x + f1.x) + (f2.x + f3.x);
            ay += (f0.y + f1.y) + (f2.y + f3.y);
            az += (f0.z + f1.z) + (f2.z + f3.z);
            aw += (f0.w + f1.w) + (f2.w + f3.w);
        }
        for (; e < s1; e += 2) {
            const float4 f0 = feat4[(size_t)ssrc[e] * 32 + q];
            ax += f0.x; ay += f0.y; az += f0.z; aw += f0.w;
        }
        ax += __shfl_xor(ax, 32);
        ay += __shfl_xor(ay, 32);
        az += __shfl_xor(az, 32);
        aw += __shfl_xor(aw, 32);
        if (half == 0) {
            float4 r;
            r.x = ax; r.y = ay; r.z = az; r.w = aw;
            ((float4*)(out + (size_t)v * F))[q] = r;
        }
    }
}

// R11-proven VALU linear (mid path).
__global__ __launch_bounds__(LINB) void linear_relu_kernel(
        float* __restrict__ h, const __half* __restrict__ wTh,
        const float* __restrict__ b, int N) {
    __shared__ __align__(16) float sA[ROWS2][132];
    const int tid = threadIdx.x;
    const int row0 = blockIdx.x * ROWS2;

    for (int i = tid; i < ROWS2 * 32; i += LINB) {
        int r = i >> 5, q = i & 31;
        int gr = row0 + r;
        float4 v = make_float4(0.f, 0.f, 0.f, 0.f);
        if (gr < N) v = ((const float4*)(h + (size_t)gr * F))[q];
        *((float4*)&sA[r][q << 2]) = v;
    }
    __syncthreads();

    const int tr = tid >> 5;
    const int tc = tid & 31;
    float acc[4][4];
#pragma unroll
    for (int i = 0; i < 4; ++i)
#pragma unroll
        for (int j = 0; j < 4; ++j) acc[i][j] = 0.f;

    const uint2* wTh2 = (const uint2*)wTh;
    uint2 u0 = wTh2[0 * 32 + tc];
    uint2 u1 = wTh2[1 * 32 + tc];
    uint2 u2 = wTh2[2 * 32 + tc];
    uint2 u3 = wTh2[3 * 32 + tc];

#pragma unroll 1
    for (int k = 0; k < F - 4; k += 4) {
        const uint2 p0 = wTh2[(k + 4) * 32 + tc];
        const uint2 p1 = wTh2[(k + 5) * 32 + tc];
        const uint2 p2 = wTh2[(k + 6) * 32 + tc];
        const uint2 p3 = wTh2[(k + 7) * 32 + tc];
        const float4 w0 = h8_to_f4(u0);
        const float4 w1 = h8_to_f4(u1);
        const float4 w2 = h8_to_f4(u2);
        const float4 w3 = h8_to_f4(u3);
#pragma unroll
        for (int i = 0; i < 4; ++i) {
            const float4 a = *(const float4*)&sA[tr * 4 + i][k];
            acc[i][0] += a.x * w0.x + a.y * w1.x + a.z * w2.x + a.w * w3.x;
            acc[i][1] += a.x * w0.y + a.y * w1.y + a.z * w2.y + a.w * w3.y;
            acc[i][2] += a.x * w0.z + a.y * w1.z + a.z * w2.z + a.w * w3.z;
            acc[i][3] += a.x * w0.w + a.y * w1.w + a.z * w2.w + a.w * w3.w;
        }
        u0 = p0; u1 = p1; u2 = p2; u3 = p3;
    }
    {
        const int k = F - 4;
        const float4 w0 = h8_to_f4(u0);
        const float4 w1 = h8_to_f4(u1);
        const float4 w2 = h8_to_f4(u2);
        const float4 w3 = h8_to_f4(u3);
#pragma unroll
        for (int i = 0; i < 4; ++i) {
            const float4 a = *(const float4*)&sA[tr * 4 + i][k];
            acc[i][0] += a.x * w0.x + a.y * w1.x + a.z * w2.x + a.w * w3.x;
            acc[i][1] += a.x * w0.y + a.y * w1.y + a.z * w2.y + a.w * w3.y;
            acc[i][2] += a.x * w0.z + a.y * w1.z + a.z * w2.z + a.w * w3.z;
            acc[i][3] += a.x * w0.w + a.y * w1.w + a.z * w2.w + a.w * w3.w;
        }
    }

    const float4 bias = ((const float4*)b)[tc];
#pragma unroll
    for (int i = 0; i < 4; ++i) {
        int gr = row0 + tr * 4 + i;
        if (gr < N) {
            float4 o;
            o.x = fmaxf(acc[i][0] + bias.x, 0.f);
            o.y = fmaxf(acc[i][1] + bias.y, 0.f);
            o.z = fmaxf(acc[i][2] + bias.z, 0.f);
            o.w = fmaxf(acc[i][3] + bias.w, 0.f);
            ((float4*)(h + (size_t)gr * F))[tc] = o;
        }
    }
}

// ---------------- ws-too-small fallback path (R1-proven) ----------------
__global__ void zero_f4_kernel(float4* __restrict__ out, int n4) {
    int i = blockIdx.x * blockDim.x + threadIdx.x;
    if (i < n4) out[i] = make_float4(0.f, 0.f, 0.f, 0.f);
}

__global__ void scatter_atomic_kernel(const float* __restrict__ feat,
                                      const int* __restrict__ src,
                                      const int* __restrict__ dst,
                                      float* __restrict__ agg, int E) {
    int gid = blockIdx.x * blockDim.x + threadIdx.x;
    int e = gid >> 5;
    if (e >= E) return;
    int q = gid & 31;
    int s = src[e];
    int d = dst[e];
    const float4 v = ((const float4*)(feat + (size_t)s * F))[q];
    float* o = agg + (size_t)d * F + (q << 2);
    atomicAdd(o + 0, v.x);
    atomicAdd(o + 1, v.y);
    atomicAdd(o + 2, v.z);
    atomicAdd(o + 3, v.w);
}

__global__ __launch_bounds__(256) void linear_relu_w_kernel(
        float* __restrict__ h, const float* __restrict__ W,
        const float* __restrict__ b, int N) {
    __shared__ __align__(16) float sA[64][132];
    const int tid = threadIdx.x;
    const int row0 = blockIdx.x * 64;

    for (int i = tid; i < 64 * 32; i += 256) {
        int r = i >> 5, q = i & 31;
        int gr = row0 + r;
        float4 v = make_float4(0.f, 0.f, 0.f, 0.f);
        if (gr < N) v = ((const float4*)(h + (size_t)gr * F))[q];
        *((float4*)&sA[r][q << 2]) = v;
    }
    __syncthreads();

    const int tr = tid >> 5;
    const int tc = tid & 31;
    float acc[8][4];
#pragma unroll
    for (int i = 0; i < 8; ++i)
#pragma unroll
        for (int j = 0; j < 4; ++j) acc[i][j] = 0.f;

    const float* Wr0 = W + (size_t)(tc * 4 + 0) * F;
    const float* Wr1 = W + (size_t)(tc * 4 + 1) * F;
    const float* Wr2 = W + (size_t)(tc * 4 + 2) * F;
    const float* Wr3 = W + (size_t)(tc * 4 + 3) * F;

    for (int k = 0; k < F; k += 4) {
        const float4 w0 = *(const float4*)&Wr0[k];
        const float4 w1 = *(const float4*)&Wr1[k];
        const float4 w2 = *(const float4*)&Wr2[k];
        const float4 w3 = *(const float4*)&Wr3[k];
#pragma unroll
        for (int i = 0; i < 8; ++i) {
            const float4 a = *(const float4*)&sA[tr * 8 + i][k];
            acc[i][0] += a.x * w0.x + a.y * w0.y + a.z * w0.z + a.w * w0.w;
            acc[i][1] += a.x * w1.x + a.y * w1.y + a.z * w1.z + a.w * w1.w;
            acc[i][2] += a.x * w2.x + a.y * w2.y + a.z * w2.z + a.w * w2.w;
            acc[i][3] += a.x * w3.x + a.y * w3.y + a.z * w3.z + a.w * w3.w;
        }
    }

    const float4 bias = ((const float4*)b)[tc];
#pragma unroll
    for (int i = 0; i < 8; ++i) {
        int gr = row0 + tr * 8 + i;
        if (gr < N) {
            float4 o;
            o.x = fmaxf(acc[i][0] + bias.x, 0.f);
            o.y = fmaxf(acc[i][1] + bias.y, 0.f);
            o.z = fmaxf(acc[i][2] + bias.z, 0.f);
            o.w = fmaxf(acc[i][3] + bias.w, 0.f);
            ((float4*)(h + (size_t)gr * F))[tc] = o;
        }
    }
}

extern "C" void kernel_launch(void* const* d_in, const int* in_sizes, int n_in,
                              void* d_out, int out_size, void* d_ws, size_t ws_size,
                              hipStream_t stream) {
    const float* feat = (const float*)d_in[0];
    const int*   src  = (const int*)d_in[1];
    const int*   dst  = (const int*)d_in[2];
    const float* W    = (const float*)d_in[3];
    const float* b    = (const float*)d_in[4];
    float* out = (float*)d_out;

    const int N = in_sizes[0] / F;   // 50000
    const int E = in_sizes[1];       // 800000
    const int NT = (N + TILE - 1) / TILE;          // 196
    const int NCHUNK = (E + CHUNK - 1) / CHUNK;    // 196
    const int NB = (N + SCAN_TILE - 1) / SCAN_TILE;

    auto align4 = [](size_t x) { return (x + 3) & ~(size_t)3; };

    // main-path ws layout (4B units, 16B-aligned regions):
    // featH[N*64] | woh[F*F/2] | offsets[N+1] | bucketBase[NT+1] | wcur[4]
    // | blkCnt[NT*NCHUNK] | blkOff[NT*NCHUNK] | edgebuf[E] | ssrc[E]
    const size_t o_featH = 0;
    const size_t o_woh   = align4(o_featH + (size_t)N * 64);
    const size_t o_offs  = align4(o_woh + (size_t)(F * F) / 2);
    const size_t o_bb    = align4(o_offs + (size_t)N + 1);
    const size_t o_wcur  = align4(o_bb + (size_t)NT + 1);
    const size_t o_blk   = align4(o_wcur + 4);
    const size_t o_boff  = align4(o_blk + (size_t)NT * NCHUNK);
    const size_t o_ebuf  = align4(o_boff + (size_t)NT * NCHUNK);
    const size_t o_ssrc  = align4(o_ebuf + (size_t)E);
    const size_t need_main = (o_ssrc + (size_t)E) * sizeof(int);

    // mid-path (round-11) layout: wTh first
    const size_t csr_ints = (size_t)(F * F) / 2 + N + (N + 1) + N + 260 + E;
    const size_t need_mid = csr_ints * sizeof(int);
    const bool nb_ok = (NB < 256) || ((N & (SCAN_TILE - 1)) != 0 && NB <= 256);

    if (ws_size >= need_main && NT <= 256 && N < (1 << 24)) {
        unsigned int* featH = (unsigned int*)d_ws;
        __half* woh          = (__half*)((int*)d_ws + o_woh);
        int* offsets         = (int*)d_ws + o_offs;
        int* bucketBase      = (int*)d_ws + o_bb;
        int* wcur            = (int*)d_ws + o_wcur;
        int* blkCnt          = (int*)d_ws + o_blk;
        int* blkOff          = (int*)d_ws + o_boff;
        unsigned int* edgebuf = (unsigned int*)((int*)d_ws + o_ebuf);
        int* ssrc            = (int*)d_ws + o_ssrc;

        const int NF4 = N * 32;
        const int nprep = (NF4 + 255) / 256;
        prep_count_kernel<<<NCHUNK + nprep, 256, 0, stream>>>(
            feat, featH, W, woh, offsets, dst, blkCnt, wcur, N, NF4, E, NT, NCHUNK);
        binA_scan_kernel<<<NT, 256, 0, stream>>>(blkCnt, blkOff, bucketBase, E, NT, NCHUNK);
        binA_scatter_kernel<<<NCHUNK, 256, 0, stream>>>(src, dst, blkOff, edgebuf, E, NT, NCHUNK);
        build_tile_kernel<<<NT, 256, 0, stream>>>(edgebuf, bucketBase, offsets, ssrc, N, NT);
        const int ntiles = (N + 15) / 16;
        const int ablocks = ntiles < 2048 ? ntiles : 2048;
        agg_mfma_kernel<<<ablocks, 256, 0, stream>>>(
            (const uint4*)featH, ssrc, offsets, bucketBase,
            (const uint4*)woh, b, wcur, out, N);
    } else if (ws_size >= need_mid && nb_ok) {
        __half* wTh    = (__half*)d_ws;
        int* counts    = (int*)d_ws + (F * F) / 2;
        int* offsets   = counts + N;
        int* cursor    = offsets + (N + 1);
        int* blockSums = cursor + N;
        int* ssrc      = blockSums + 260;

        prep2_kernel<<<(N + 255) / 256, 256, 0, stream>>>(W, wTh, counts, N);
        hist_kernel<<<(E + 255) / 256, 256, 0, stream>>>(dst, counts, E);
        scan1_kernel<<<NB, 256, 0, stream>>>(counts, offsets, cursor, blockSums, N);
        scan2_kernel<<<1, 256, 0, stream>>>(blockSums, offsets, NB, N);
        place_kernel<<<(E + 255) / 256, 256, 0, stream>>>(src, dst, cursor, blockSums, ssrc, E);
        agg_kernel<<<2048, 256, 0, stream>>>(feat, ssrc, offsets, blockSums, out, N);
        linear_relu_kernel<<<(N + ROWS2 - 1) / ROWS2, LINB, 0, stream>>>(out, wTh, b, N);
    } else {
        const int n4 = N * (F / 4);
        zero_f4_kernel<<<(n4 + 255) / 256, 256, 0, stream>>>((float4*)out, n4);
        const int sthreads = E * 32;
        scatter_atomic_kernel<<<(sthreads + 255) / 256, 256, 0, stream>>>(feat, src, dst, out, E);
        linear_relu_w_kernel<<<(N + 63) / 64, 256, 0, stream>>>(out, W, b, N);
    }
}

// Round 16
// 169.775 us; speedup vs baseline: 1.4919x; 1.4919x over previous
//
#include <hip/hip_runtime.h>
#include <hip/hip_fp16.h>

#define F 128
#define TILE 256          // nodes per dst-tile (main path)
#define TSH 8             // log2(TILE)
#define CHUNK 4096        // edges per bin block
#define BCAP 8192         // LDS stage capacity (ints) in build_tile; avg tile = 4082
#define ROWS2 32          // mid-path linear tile rows (R11-proven VALU kernel)
#define LINB 256
#define SCAN_TILE 1024    // mid-path (round-3 proven) tile

typedef _Float16 f16x8 __attribute__((ext_vector_type(8)));
typedef float f32x4 __attribute__((ext_vector_type(4)));

__device__ inline float4 h8_to_f4(uint2 u) {
    union { unsigned int x; __half2 h; } a, b;
    a.x = u.x; b.x = u.y;
    const float2 lo = __half22float2(a.h);
    const float2 hi = __half22float2(b.h);
    return make_float4(lo.x, lo.y, hi.x, hi.y);
}

// ============================================================================
// Fused prep + A1 count (round-12 proven):
//  blocks [0, NCHUNK): per-chunk tile histogram into LDS -> blkCnt.
//  blocks [NCHUNK, ...): feat fp32->fp16; W fp32->fp16 element-wise ([o][k]
//    = MFMA B-operand layout); offsets[N] fix.
// ============================================================================
__global__ __launch_bounds__(256) void prep_count_kernel(
        const float* __restrict__ feat, unsigned int* __restrict__ featH,
        const float* __restrict__ W, __half* __restrict__ woh,
        int* __restrict__ offsets, const int* __restrict__ dst,
        int* __restrict__ blkCnt,
        int N, int NF4, int E, int NT, int NCHUNK) {
    __shared__ int h[256];
    const int tid = threadIdx.x;
    const int bid = blockIdx.x;
    if (bid < NCHUNK) {
        h[tid] = 0;
        __syncthreads();
        const int e0 = bid * CHUNK;
        const int n = min(CHUNK, E - e0);
        for (int i = tid; i < n; i += 256) atomicAdd(&h[dst[e0 + i] >> TSH], 1);
        __syncthreads();
        if (tid < NT) blkCnt[(size_t)tid * NCHUNK + bid] = h[tid];
    } else {
        const int i = (bid - NCHUNK) * 256 + tid;
        if (i < NF4) {
            const float4 v = ((const float4*)feat)[i];
            union { __half2 h2; unsigned int u; } a, b;
            a.h2 = __floats2half2_rn(v.x, v.y);
            b.h2 = __floats2half2_rn(v.z, v.w);
            ((uint2*)featH)[i] = make_uint2(a.u, b.u);
        }
        if (i < F * F) woh[i] = __float2half(W[i]);
        if (i == 0 && (N & (TILE - 1)) == 0) offsets[N] = 0;
    }
}

// ============================================================================
// A2 (parallel, round-5 proven): one block per tile row t.
// ============================================================================
__global__ __launch_bounds__(256) void binA_scan_kernel(
        const int* __restrict__ blkCnt, int* __restrict__ blkOff,
        int* __restrict__ bucketBase, int E, int NT, int NCHUNK) {
    __shared__ int red[256];
    const int t = blockIdx.x;
    const int tid = threadIdx.x;

    const int lim = t * NCHUNK;
    int s = 0;
    for (int i = tid; i < lim; i += 256) s += blkCnt[i];
    red[tid] = s;
    __syncthreads();
    for (int off = 128; off > 0; off >>= 1) {
        if (tid < off) red[tid] += red[tid + off];
        __syncthreads();
    }
    const int base = red[0];
    __syncthreads();

    int carry = base;
    for (int c0 = 0; c0 < NCHUNK; c0 += 256) {
        const int b = c0 + tid;
        const int v = (b < NCHUNK) ? blkCnt[(size_t)t * NCHUNK + b] : 0;
        red[tid] = v;
        __syncthreads();
        for (int off = 1; off < 256; off <<= 1) {
            int tv = (tid >= off) ? red[tid - off] : 0;
            __syncthreads();
            red[tid] += tv;
            __syncthreads();
        }
        const int excl = red[tid] - v;
        if (b < NCHUNK) blkOff[(size_t)t * NCHUNK + b] = carry + excl;
        const int tot = red[255];
        __syncthreads();
        carry += tot;
    }
    if (tid == 0) {
        bucketBase[t] = base;
        if (t == 0) bucketBase[NT] = E;
    }
}

// ============================================================================
// A3: deterministic scatter (round-5 proven).
// ============================================================================
__global__ __launch_bounds__(256) void binA_scatter_kernel(
        const int* __restrict__ src, const int* __restrict__ dst,
        const int* __restrict__ blkOff,
        unsigned int* __restrict__ edgebuf, int E, int NT, int NCHUNK) {
    __shared__ int h[256];
    __shared__ int lds2[256];
    __shared__ int cstart[256];
    __shared__ uint2 stage[CHUNK];
    const int tid = threadIdx.x, b = blockIdx.x;
    h[tid] = 0;
    __syncthreads();
    const int e0 = b * CHUNK;
    const int n = min(CHUNK, E - e0);
    for (int i = tid; i < n; i += 256) atomicAdd(&h[dst[e0 + i] >> TSH], 1);
    __syncthreads();
    const int myc = h[tid];
    lds2[tid] = myc;
    __syncthreads();
    for (int off = 1; off < 256; off <<= 1) {
        int t = (tid >= off) ? lds2[tid - off] : 0;
        __syncthreads();
        lds2[tid] += t;
        __syncthreads();
    }
    const int runstart = lds2[tid] - myc;
    if (tid < NT) cstart[tid] = blkOff[(size_t)tid * NCHUNK + b] - runstart;
    h[tid] = runstart;
    __syncthreads();
    for (int i = tid; i < n; i += 256) {
        const int e = e0 + i;
        const int d = dst[e];
        const int p = atomicAdd(&h[d >> TSH], 1);
        stage[p] = make_uint2((unsigned)src[e], (unsigned)d);
    }
    __syncthreads();
    for (int i = tid; i < n; i += 256) {
        const uint2 v = stage[i];
        const int t = (int)v.y >> TSH;
        edgebuf[cstart[t] + i] = (v.x << 8) | (v.y & 255u);
    }
}

// ============================================================================
// B: per-tile CSR finalize (round-5 proven).
// ============================================================================
__global__ __launch_bounds__(256) void build_tile_kernel(
        const unsigned int* __restrict__ edgebuf, const int* __restrict__ bucketBase,
        int* __restrict__ offsets, int* __restrict__ ssrc, int N, int NT) {
    __shared__ int h[TILE];
    __shared__ int excl[TILE];
    __shared__ int stage[BCAP];
    const int t = blockIdx.x, tid = threadIdx.x;
    const int s0 = bucketBase[t], s1 = bucketBase[t + 1];
    const int cnt = s1 - s0;
    const int n0 = t << TSH;
    const int n1 = min(n0 + TILE, N);
    h[tid] = 0;
    __syncthreads();
    for (int i = tid; i < cnt; i += 256)
        atomicAdd(&h[(int)(edgebuf[s0 + i] & 255u)], 1);
    __syncthreads();
    const int myv = h[tid];
    excl[tid] = myv;
    __syncthreads();
    for (int off = 1; off < 256; off <<= 1) {
        int tv = (tid >= off) ? excl[tid - off] : 0;
        __syncthreads();
        excl[tid] += tv;
        __syncthreads();
    }
    const int ex = excl[tid] - myv;
    const int v = n0 + tid;
    if (v < n1) offsets[v] = ex;
    if (tid == 255 && n1 == N && (N & (TILE - 1)) != 0) offsets[N] = excl[255];
    h[tid] = ex;
    __syncthreads();
    if (cnt <= BCAP) {
        for (int i = tid; i < cnt; i += 256) {
            const unsigned int e = edgebuf[s0 + i];
            const int p = atomicAdd(&h[(int)(e & 255u)], 1);
            stage[p] = (int)(e >> 8);
        }
        __syncthreads();
        for (int i = tid; i < cnt; i += 256) ssrc[s0 + i] = stage[i];
    } else {
        for (int i = tid; i < cnt; i += 256) {
            const unsigned int e = edgebuf[s0 + i];
            const int p = atomicAdd(&h[(int)(e & 255u)], 1);
            ssrc[s0 + p] = (int)(e >> 8);
        }
    }
}

// ============================================================================
// FUSED gather + MFMA, v4: 2-wave (128t) block per 16-node tile, static grid.
// History: R13 1-wave/tile = 3 blocks/CU (26% occ). R14 4-wave 256t block =
// 3125 blocks @ 8/CU = 1.53 scheduling rounds (56.5% occ, 46.6us, BEST).
// R15 persistent work-steal = 127us REGRESSION (inter-tile barrier serialized
// phase-B -> next phase-A; block retirement is the free pipeline).
// v4: 128-thread blocks -> 16 resident blocks/CU (thread-slot cap) -> all
// 3125 blocks co-resident in ONE scheduling round, same 32 waves/CU, blocks
// still retire. Phase A: each of 2 waves gathers 8 nodes into shared LDS
// tile. One barrier. Phase B: each wave computes 4 col-groups of the
// R12-verified 16x128 MFMA tile.
// ============================================================================
__global__ __launch_bounds__(128) void agg_mfma_kernel(
        const uint4* __restrict__ fH,
        const int* __restrict__ ssrc,
        const int* __restrict__ offs,
        const int* __restrict__ base,
        const uint4* __restrict__ woh4,   // W[o][k] fp16, 128 rows x 16 uint4
        const float* __restrict__ bias,
        float* __restrict__ out, int N) {
    __shared__ __align__(16) uint4 buf[16 * 17];   // 16 rows x 272B = 4.25KB
    const int tid = threadIdx.x;
    const int wid = tid >> 6;     // 0..1
    const int lane = tid & 63;
    const int g = lane >> 4;      // edge slot (A) / k-quarter (B)
    const int q = lane & 15;      // 16B chunk (A) / m16 (B)
    const int v0 = blockIdx.x << 4;

    // ---- phase A: wave wid aggregates its 8 nodes into LDS ----
#pragma unroll 1
    for (int t = 0; t < 8; ++t) {
        const int r16 = wid * 8 + t;
        const int v = v0 + r16;
        float a[8];
#pragma unroll
        for (int j = 0; j < 8; ++j) a[j] = 0.f;
        if (v < N) {
            const int s0 = offs[v] + base[v >> TSH];
            const int s1 = offs[v + 1] + base[(v + 1) >> TSH];
            int e = s0 + g;
            for (; e + 4 < s1; e += 8) {
                const int i0 = ssrc[e], i1 = ssrc[e + 4];
                const uint4 u0 = fH[(size_t)i0 * 16 + q];
                const uint4 u1 = fH[(size_t)i1 * 16 + q];
                {
                    union { unsigned int u; __half2 h; } c0, c1, c2, c3;
                    c0.u = u0.x; c1.u = u0.y; c2.u = u0.z; c3.u = u0.w;
                    const float2 f0 = __half22float2(c0.h);
                    const float2 f1 = __half22float2(c1.h);
                    const float2 f2 = __half22float2(c2.h);
                    const float2 f3 = __half22float2(c3.h);
                    a[0] += f0.x; a[1] += f0.y; a[2] += f1.x; a[3] += f1.y;
                    a[4] += f2.x; a[5] += f2.y; a[6] += f3.x; a[7] += f3.y;
                }
                {
                    union { unsigned int u; __half2 h; } c0, c1, c2, c3;
                    c0.u = u1.x; c1.u = u1.y; c2.u = u1.z; c3.u = u1.w;
                    const float2 f0 = __half22float2(c0.h);
                    const float2 f1 = __half22float2(c1.h);
                    const float2 f2 = __half22float2(c2.h);
                    const float2 f3 = __half22float2(c3.h);
                    a[0] += f0.x; a[1] += f0.y; a[2] += f1.x; a[3] += f1.y;
                    a[4] += f2.x; a[5] += f2.y; a[6] += f3.x; a[7] += f3.y;
                }
            }
            for (; e < s1; e += 4) {
                const uint4 u0 = fH[(size_t)ssrc[e] * 16 + q];
                union { unsigned int u; __half2 h; } c0, c1, c2, c3;
                c0.u = u0.x; c1.u = u0.y; c2.u = u0.z; c3.u = u0.w;
                const float2 f0 = __half22float2(c0.h);
                const float2 f1 = __half22float2(c1.h);
                const float2 f2 = __half22float2(c2.h);
                const float2 f3 = __half22float2(c3.h);
                a[0] += f0.x; a[1] += f0.y; a[2] += f1.x; a[3] += f1.y;
                a[4] += f2.x; a[5] += f2.y; a[6] += f3.x; a[7] += f3.y;
            }
        }
#pragma unroll
        for (int j = 0; j < 8; ++j) {
            a[j] += __shfl_xor(a[j], 16);
            a[j] += __shfl_xor(a[j], 32);
        }
        if (g == 0) {
            union { __half2 h2; unsigned int u; } p0, p1, p2, p3;
            p0.h2 = __floats2half2_rn(a[0], a[1]);
            p1.h2 = __floats2half2_rn(a[2], a[3]);
            p2.h2 = __floats2half2_rn(a[4], a[5]);
            p3.h2 = __floats2half2_rn(a[6], a[7]);
            buf[r16 * 17 + q] = make_uint4(p0.u, p1.u, p2.u, p3.u);
        }
    }
    __syncthreads();

    // ---- phase B: wave wid computes col-groups 4*wid .. 4*wid+3 ----
    union U { uint4 u; f16x8 h; };
    U af0, af1, af2, af3;
    af0.u = buf[q * 17 + (g + 0)];
    af1.u = buf[q * 17 + (g + 4)];
    af2.u = buf[q * 17 + (g + 8)];
    af3.u = buf[q * 17 + (g + 12)];

#pragma unroll
    for (int j = 0; j < 4; ++j) {
        const int gg = wid * 4 + j;
        const uint4* wrow = woh4 + (size_t)(gg * 16 + q) * 16 + g;
        U b0, b1, b2, b3;
        b0.u = wrow[0]; b1.u = wrow[4]; b2.u = wrow[8]; b3.u = wrow[12];
        f32x4 acc = {0.f, 0.f, 0.f, 0.f};
        acc = __builtin_amdgcn_mfma_f32_16x16x32_f16(af0.h, b0.h, acc, 0, 0, 0);
        acc = __builtin_amdgcn_mfma_f32_16x16x32_f16(af1.h, b1.h, acc, 0, 0, 0);
        acc = __builtin_amdgcn_mfma_f32_16x16x32_f16(af2.h, b2.h, acc, 0, 0, 0);
        acc = __builtin_amdgcn_mfma_f32_16x16x32_f16(af3.h, b3.h, acc, 0, 0, 0);
        const float bv = bias[gg * 16 + q];
#pragma unroll
        for (int r = 0; r < 4; ++r) {
            const int gr = v0 + g * 4 + r;
            if (gr < N)
                out[(size_t)gr * F + gg * 16 + q] = fmaxf(acc[r] + bv, 0.f);
        }
    }
}

// ================= mid path (round-3/11 proven chain, fp32 gather) ==========
__global__ void prep2_kernel(const float* __restrict__ W, __half* __restrict__ wTh,
                             int* __restrict__ counts, int N) {
    int i = blockIdx.x * 256 + threadIdx.x;
    if (i < F * F) {
        int o = i >> 7, k = i & 127;
        wTh[k * F + o] = __float2half(W[i]);
    }
    if (i < N) counts[i] = 0;
}

__global__ void hist_kernel(const int* __restrict__ dst, int* __restrict__ counts, int E) {
    int e = blockIdx.x * blockDim.x + threadIdx.x;
    if (e < E) atomicAdd(&counts[dst[e]], 1);
}

__global__ __launch_bounds__(256) void scan1_kernel(const int* __restrict__ counts,
                                                    int* __restrict__ offsets,
                                                    int* __restrict__ cursor,
                                                    int* __restrict__ blockSums, int N) {
    __shared__ int lds[256];
    const int tid = threadIdx.x;
    const int i0 = blockIdx.x * SCAN_TILE + tid * 4;
    int v[4];
    int s = 0;
#pragma unroll
    for (int j = 0; j < 4; ++j) {
        int i = i0 + j;
        v[j] = (i < N) ? counts[i] : 0;
        s += v[j];
    }
    lds[tid] = s;
    __syncthreads();
    for (int off = 1; off < 256; off <<= 1) {
        int t = (tid >= off) ? lds[tid - off] : 0;
        __syncthreads();
        lds[tid] += t;
        __syncthreads();
    }
    int excl = lds[tid] - s;
#pragma unroll
    for (int j = 0; j < 4; ++j) {
        int i = i0 + j;
        if (i < N) {
            offsets[i] = excl;
            cursor[i] = excl;
        } else if (i == N) {
            offsets[N] = excl;
        }
        excl += v[j];
    }
    if (tid == 255) blockSums[blockIdx.x] = lds[255];
}

__global__ __launch_bounds__(256) void scan2_kernel(int* __restrict__ blockSums,
                                                    int* __restrict__ offsets,
                                                    int NB, int N) {
    __shared__ int lds[256];
    const int tid = threadIdx.x;
    int s = (tid < NB) ? blockSums[tid] : 0;
    lds[tid] = s;
    __syncthreads();
    for (int off = 1; off < 256; off <<= 1) {
        int t = (tid >= off) ? lds[tid - off] : 0;
        __syncthreads();
        lds[tid] += t;
        __syncthreads();
    }
    if (tid < NB) blockSums[tid] = lds[tid] - s;
    if (tid == NB && NB < 256) blockSums[NB] = lds[255];
    if (tid == 0 && (N & (SCAN_TILE - 1)) == 0) offsets[N] = 0;
}

__global__ void place_kernel(const int* __restrict__ src, const int* __restrict__ dst,
                             int* __restrict__ cursor, const int* __restrict__ base,
                             int* __restrict__ ssrc, int E) {
    int e = blockIdx.x * blockDim.x + threadIdx.x;
    if (e < E) {
        int d = dst[e];
        int pos = atomicAdd(&cursor[d], 1) + base[d >> 10];
        ssrc[pos] = src[e];
    }
}

__global__ __launch_bounds__(256) void agg_kernel(const float* __restrict__ feat,
                                                  const int* __restrict__ ssrc,
                                                  const int* __restrict__ offs,
                                                  const int* __restrict__ base,
                                                  float* __restrict__ out, int N) {
    const int gwave = (blockIdx.x * blockDim.x + threadIdx.x) >> 6;
    const int lane = threadIdx.x & 63;
    const int half = lane >> 5;
    const int q = lane & 31;
    const int nwaves = (gridDim.x * blockDim.x) >> 6;
    const float4* feat4 = (const float4*)feat;
    for (int v = gwave; v < N; v += nwaves) {
        const int s0 = offs[v] + base[v >> 10];
        const int s1 = offs[v + 1] + base[(v + 1) >> 10];
        float ax = 0.f, ay = 0.f, az = 0.f, aw = 0.f;
        int e = s0 + half;
        for (; e + 6 < s1; e += 8) {
            int i0 = ssrc[e], i1 = ssrc[e + 2], i2 = ssrc[e + 4], i3 = ssrc[e + 6];
            const float4 f0 = feat4[(size_t)i0 * 32 + q];
            const float4 f1 = feat4[(size_t)i1 * 32 + q];
            const float4 f2 = feat4[(size_t)i2 * 32 + q];
            const float4 f3 = feat4[(size_t)i3 * 32 + q];
            ax += (f0.x + f1.x) + (f2.x + f3.x);
            ay += (f0.y + f1.y) + (f2.y + f3.y);
            az += (f0.z + f1.z) + (f2.z + f3.z);
            aw += (f0.w + f1.w) + (f2.w + f3.w);
        }
        for (; e < s1; e += 2) {
            const float4 f0 = feat4[(size_t)ssrc[e] * 32 + q];
            ax += f0.x; ay += f0.y; az += f0.z; aw += f0.w;
        }
        ax += __shfl_xor(ax, 32);
        ay += __shfl_xor(ay, 32);
        az += __shfl_xor(az, 32);
        aw += __shfl_xor(aw, 32);
        if (half == 0) {
            float4 r;
            r.x = ax; r.y = ay; r.z = az; r.w = aw;
            ((float4*)(out + (size_t)v * F))[q] = r;
        }
    }
}

// R11-proven VALU linear (mid path).
__global__ __launch_bounds__(LINB) void linear_relu_kernel(
        float* __restrict__ h, const __half* __restrict__ wTh,
        const float* __restrict__ b, int N) {
    __shared__ __align__(16) float sA[ROWS2][132];
    const int tid = threadIdx.x;
    const int row0 = blockIdx.x * ROWS2;

    for (int i = tid; i < ROWS2 * 32; i += LINB) {
        int r = i >> 5, q = i & 31;
        int gr = row0 + r;
        float4 v = make_float4(0.f, 0.f, 0.f, 0.f);
        if (gr < N) v = ((const float4*)(h + (size_t)gr * F))[q];
        *((float4*)&sA[r][q << 2]) = v;
    }
    __syncthreads();

    const int tr = tid >> 5;
    const int tc = tid & 31;
    float acc[4][4];
#pragma unroll
    for (int i = 0; i < 4; ++i)
#pragma unroll
        for (int j = 0; j < 4; ++j) acc[i][j] = 0.f;

    const uint2* wTh2 = (const uint2*)wTh;
    uint2 u0 = wTh2[0 * 32 + tc];
    uint2 u1 = wTh2[1 * 32 + tc];
    uint2 u2 = wTh2[2 * 32 + tc];
    uint2 u3 = wTh2[3 * 32 + tc];

#pragma unroll 1
    for (int k = 0; k < F - 4; k += 4) {
        const uint2 p0 = wTh2[(k + 4) * 32 + tc];
        const uint2 p1 = wTh2[(k + 5) * 32 + tc];
        const uint2 p2 = wTh2[(k + 6) * 32 + tc];
        const uint2 p3 = wTh2[(k + 7) * 32 + tc];
        const float4 w0 = h8_to_f4(u0);
        const float4 w1 = h8_to_f4(u1);
        const float4 w2 = h8_to_f4(u2);
        const float4 w3 = h8_to_f4(u3);
#pragma unroll
        for (int i = 0; i < 4; ++i) {
            const float4 a = *(const float4*)&sA[tr * 4 + i][k];
            acc[i][0] += a.x * w0.x + a.y * w1.x + a.z * w2.x + a.w * w3.x;
            acc[i][1] += a.x * w0.y + a.y * w1.y + a.z * w2.y + a.w * w3.y;
            acc[i][2] += a.x * w0.z + a.y * w1.z + a.z * w2.z + a.w * w3.z;
            acc[i][3] += a.x * w0.w + a.y * w1.w + a.z * w2.w + a.w * w3.w;
        }
        u0 = p0; u1 = p1; u2 = p2; u3 = p3;
    }
    {
        const int k = F - 4;
        const float4 w0 = h8_to_f4(u0);
        const float4 w1 = h8_to_f4(u1);
        const float4 w2 = h8_to_f4(u2);
        const float4 w3 = h8_to_f4(u3);
#pragma unroll
        for (int i = 0; i < 4; ++i) {
            const float4 a = *(const float4*)&sA[tr * 4 + i][k];
            acc[i][0] += a.x * w0.x + a.y * w1.x + a.z * w2.x + a.w * w3.x;
            acc[i][1] += a.x * w0.y + a.y * w1.y + a.z * w2.y + a.w * w3.y;
            acc[i][2] += a.x * w0.z + a.y * w1.z + a.z * w2.z + a.w * w3.z;
            acc[i][3] += a.x * w0.w + a.y * w1.w + a.z * w2.w + a.w * w3.w;
        }
    }

    const float4 bias = ((const float4*)b)[tc];
#pragma unroll
    for (int i = 0; i < 4; ++i) {
        int gr = row0 + tr * 4 + i;
        if (gr < N) {
            float4 o;
            o.x = fmaxf(acc[i][0] + bias.x, 0.f);
            o.y = fmaxf(acc[i][1] + bias.y, 0.f);
            o.z = fmaxf(acc[i][2] + bias.z, 0.f);
            o.w = fmaxf(acc[i][3] + bias.w, 0.f);
            ((float4*)(h + (size_t)gr * F))[tc] = o;
        }
    }
}

// ---------------- ws-too-small fallback path (R1-proven) ----------------
__global__ void zero_f4_kernel(float4* __restrict__ out, int n4) {
    int i = blockIdx.x * blockDim.x + threadIdx.x;
    if (i < n4) out[i] = make_float4(0.f, 0.f, 0.f, 0.f);
}

__global__ void scatter_atomic_kernel(const float* __restrict__ feat,
                                      const int* __restrict__ src,
                                      const int* __restrict__ dst,
                                      float* __restrict__ agg, int E) {
    int gid = blockIdx.x * blockDim.x + threadIdx.x;
    int e = gid >> 5;
    if (e >= E) return;
    int q = gid & 31;
    int s = src[e];
    int d = dst[e];
    const float4 v = ((const float4*)(feat + (size_t)s * F))[q];
    float* o = agg + (size_t)d * F + (q << 2);
    atomicAdd(o + 0, v.x);
    atomicAdd(o + 1, v.y);
    atomicAdd(o + 2, v.z);
    atomicAdd(o + 3, v.w);
}

__global__ __launch_bounds__(256) void linear_relu_w_kernel(
        float* __restrict__ h, const float* __restrict__ W,
        const float* __restrict__ b, int N) {
    __shared__ __align__(16) float sA[64][132];
    const int tid = threadIdx.x;
    const int row0 = blockIdx.x * 64;

    for (int i = tid; i < 64 * 32; i += 256) {
        int r = i >> 5, q = i & 31;
        int gr = row0 + r;
        float4 v = make_float4(0.f, 0.f, 0.f, 0.f);
        if (gr < N) v = ((const float4*)(h + (size_t)gr * F))[q];
        *((float4*)&sA[r][q << 2]) = v;
    }
    __syncthreads();

    const int tr = tid >> 5;
    const int tc = tid & 31;
    float acc[8][4];
#pragma unroll
    for (int i = 0; i < 8; ++i)
#pragma unroll
        for (int j = 0; j < 4; ++j) acc[i][j] = 0.f;

    const float* Wr0 = W + (size_t)(tc * 4 + 0) * F;
    const float* Wr1 = W + (size_t)(tc * 4 + 1) * F;
    const float* Wr2 = W + (size_t)(tc * 4 + 2) * F;
    const float* Wr3 = W + (size_t)(tc * 4 + 3) * F;

    for (int k = 0; k < F; k += 4) {
        const float4 w0 = *(const float4*)&Wr0[k];
        const float4 w1 = *(const float4*)&Wr1[k];
        const float4 w2 = *(const float4*)&Wr2[k];
        const float4 w3 = *(const float4*)&Wr3[k];
#pragma unroll
        for (int i = 0; i < 8; ++i) {
            const float4 a = *(const float4*)&sA[tr * 8 + i][k];
            acc[i][0] += a.x * w0.x + a.y * w0.y + a.z * w0.z + a.w * w0.w;
            acc[i][1] += a.x * w1.x + a.y * w1.y + a.z * w1.z + a.w * w1.w;
            acc[i][2] += a.x * w2.x + a.y * w2.y + a.z * w2.z + a.w * w2.w;
            acc[i][3] += a.x * w3.x + a.y * w3.y + a.z * w3.z + a.w * w3.w;
        }
    }

    const float4 bias = ((const float4*)b)[tc];
#pragma unroll
    for (int i = 0; i < 8; ++i) {
        int gr = row0 + tr * 8 + i;
        if (gr < N) {
            float4 o;
            o.x = fmaxf(acc[i][0] + bias.x, 0.f);
            o.y = fmaxf(acc[i][1] + bias.y, 0.f);
            o.z = fmaxf(acc[i][2] + bias.z, 0.f);
            o.w = fmaxf(acc[i][3] + bias.w, 0.f);
            ((float4*)(h + (size_t)gr * F))[tc] = o;
        }
    }
}

extern "C" void kernel_launch(void* const* d_in, const int* in_sizes, int n_in,
                              void* d_out, int out_size, void* d_ws, size_t ws_size,
                              hipStream_t stream) {
    const float* feat = (const float*)d_in[0];
    const int*   src  = (const int*)d_in[1];
    const int*   dst  = (const int*)d_in[2];
    const float* W    = (const float*)d_in[3];
    const float* b    = (const float*)d_in[4];
    float* out = (float*)d_out;

    const int N = in_sizes[0] / F;   // 50000
    const int E = in_sizes[1];       // 800000
    const int NT = (N + TILE - 1) / TILE;          // 196
    const int NCHUNK = (E + CHUNK - 1) / CHUNK;    // 196
    const int NB = (N + SCAN_TILE - 1) / SCAN_TILE;

    auto align4 = [](size_t x) { return (x + 3) & ~(size_t)3; };

    // main-path ws layout (4B units, 16B-aligned regions):
    // featH[N*64] | woh[F*F/2] | offsets[N+1] | bucketBase[NT+1]
    // | blkCnt[NT*NCHUNK] | blkOff[NT*NCHUNK] | edgebuf[E] | ssrc[E]
    const size_t o_featH = 0;
    const size_t o_woh   = align4(o_featH + (size_t)N * 64);
    const size_t o_offs  = align4(o_woh + (size_t)(F * F) / 2);
    const size_t o_bb    = align4(o_offs + (size_t)N + 1);
    const size_t o_blk   = align4(o_bb + (size_t)NT + 1);
    const size_t o_boff  = align4(o_blk + (size_t)NT * NCHUNK);
    const size_t o_ebuf  = align4(o_boff + (size_t)NT * NCHUNK);
    const size_t o_ssrc  = align4(o_ebuf + (size_t)E);
    const size_t need_main = (o_ssrc + (size_t)E) * sizeof(int);

    // mid-path (round-11) layout: wTh first
    const size_t csr_ints = (size_t)(F * F) / 2 + N + (N + 1) + N + 260 + E;
    const size_t need_mid = csr_ints * sizeof(int);
    const bool nb_ok = (NB < 256) || ((N & (SCAN_TILE - 1)) != 0 && NB <= 256);

    if (ws_size >= need_main && NT <= 256 && N < (1 << 24)) {
        unsigned int* featH = (unsigned int*)d_ws;
        __half* woh          = (__half*)((int*)d_ws + o_woh);
        int* offsets         = (int*)d_ws + o_offs;
        int* bucketBase      = (int*)d_ws + o_bb;
        int* blkCnt          = (int*)d_ws + o_blk;
        int* blkOff          = (int*)d_ws + o_boff;
        unsigned int* edgebuf = (unsigned int*)((int*)d_ws + o_ebuf);
        int* ssrc            = (int*)d_ws + o_ssrc;

        const int NF4 = N * 32;
        const int nprep = (NF4 + 255) / 256;
        prep_count_kernel<<<NCHUNK + nprep, 256, 0, stream>>>(
            feat, featH, W, woh, offsets, dst, blkCnt, N, NF4, E, NT, NCHUNK);
        binA_scan_kernel<<<NT, 256, 0, stream>>>(blkCnt, blkOff, bucketBase, E, NT, NCHUNK);
        binA_scatter_kernel<<<NCHUNK, 256, 0, stream>>>(src, dst, blkOff, edgebuf, E, NT, NCHUNK);
        build_tile_kernel<<<NT, 256, 0, stream>>>(edgebuf, bucketBase, offsets, ssrc, N, NT);
        const int ntiles = (N + 15) / 16;
        agg_mfma_kernel<<<ntiles, 128, 0, stream>>>(
            (const uint4*)featH, ssrc, offsets, bucketBase,
            (const uint4*)woh, b, out, N);
    } else if (ws_size >= need_mid && nb_ok) {
        __half* wTh    = (__half*)d_ws;
        int* counts    = (int*)d_ws + (F * F) / 2;
        int* offsets   = counts + N;
        int* cursor    = offsets + (N + 1);
        int* blockSums = cursor + N;
        int* ssrc      = blockSums + 260;

        prep2_kernel<<<(N + 255) / 256, 256, 0, stream>>>(W, wTh, counts, N);
        hist_kernel<<<(E + 255) / 256, 256, 0, stream>>>(dst, counts, E);
        scan1_kernel<<<NB, 256, 0, stream>>>(counts, offsets, cursor, blockSums, N);
        scan2_kernel<<<1, 256, 0, stream>>>(blockSums, offsets, NB, N);
        place_kernel<<<(E + 255) / 256, 256, 0, stream>>>(src, dst, cursor, blockSums, ssrc, E);
        agg_kernel<<<2048, 256, 0, stream>>>(feat, ssrc, offsets, blockSums, out, N);
        linear_relu_kernel<<<(N + ROWS2 - 1) / ROWS2, LINB, 0, stream>>>(out, wTh, b, N);
    } else {
        const int n4 = N * (F / 4);
        zero_f4_kernel<<<(n4 + 255) / 256, 256, 0, stream>>>((float4*)out, n4);
        const int sthreads = E * 32;
        scatter_atomic_kernel<<<(sthreads + 255) / 256, 256, 0, stream>>>(feat, src, dst, out, E);
        linear_relu_w_kernel<<<(N + 63) / 64, 256, 0, stream>>>(out, W, b, N);
    }
}